// Round 13
// baseline (23781.290 us; speedup 1.0000x reference)
//
#include <hip/hip_runtime.h>
#include <math.h>

#define T_  512
#define B_  128
#define H_  256
#define A_  18
#define G4H 1024
#define TB_ (T_*B_)

// d_out layout (floats): [logits T*B*A][baseline T*B][action T*B][hT 2*B*H][cT 2*B*H]
#define OUT_BASE  (TB_*A_)
#define OUT_ACT   (OUT_BASE + TB_)
#define OUT_HT    (OUT_ACT + TB_)
#define OUT_CT    (OUT_HT + 2*B_*H_)

// workspace (floats): PARITY-4 h per layer (slot = t&3), private c per layer,
// then 256 uint phase-stamp cells (one per WG, memset once per replay). 1.31 MB.
#define WS_H0  0                  // [4][B][H]
#define WS_H1  (4*B_*H_)          // [4][B][H]
#define WS_C0  (8*B_*H_)
#define WS_C1  (9*B_*H_)
#define WS_CTR (10*B_*H_)

// SINGLE-DISPATCH DECOUPLED-LAYER PIPELINE, v13.
// v12 post-mortem: the "+v" pins did NOT raise VGPR_Count (stuck at 128) -
// the compiler spilled the pinned fragments to scratch instead (VALUBusy
// 44->33%, +45% time). 128 VGPR is a hard regalloc ceiling here. v13 cuts DS
// reads WITHIN that budget: accumulator-major, two K-sections. acc[8][4]
// (32 regs) stays live; Section A accumulates x*Wi (x staged in stg),
// Section B accumulates h*Wh (h staged in the SAME stg buffer after a WAR
// barrier). Per q-iteration only 4 fragment float4 + 1 weight float4/row are
// live -> peak ~100 VGPR, no pins, no spill. DS reads/thread ~170 (v11) ->
// ~101 (weights once per (row,q,mat) = 64 vs v11's 128). Everything else is
// v11 verbatim: decoupled parity-4 pipeline, returning-swap cross-WG writes
// (acked at the L3 coherence point before vmcnt(0) clears), store-stamp
// arrival, relaxed system-scope polls, DPP rowsum, head-on-L0, coalesced
// tid<256 cell update, no cache-maintenance instructions.

__device__ __forceinline__ float cload(const float* p) {
    return __hip_atomic_load((float*)p, __ATOMIC_RELAXED, __HIP_MEMORY_SCOPE_SYSTEM);
}
__device__ __forceinline__ float4 cload4(const float* p) {   // 16B-aligned
    union { unsigned long long u[2]; float4 f; } r;
    r.u[0] = __hip_atomic_load((const unsigned long long*)p,
                               __ATOMIC_RELAXED, __HIP_MEMORY_SCOPE_SYSTEM);
    r.u[1] = __hip_atomic_load((const unsigned long long*)(p + 2),
                               __ATOMIC_RELAXED, __HIP_MEMORY_SCOPE_SYSTEM);
    return r.f;
}
// ordered data write: atomic exchange, returning form forced by asm sink
__device__ __forceinline__ void cswap(float* p, float v) {
    float old = __hip_atomic_exchange(p, v, __ATOMIC_RELAXED, __HIP_MEMORY_SCOPE_SYSTEM);
    asm volatile("" :: "v"(old));
}
// DPP row_ror (within 16-lane rows); 4 rotation-adds = full 16-lane sum on VALU
template<int N>
__device__ __forceinline__ float ror16(float v) {
    return __int_as_float(__builtin_amdgcn_update_dpp(
        0, __float_as_int(v), 0x120 | N, 0xF, 0xF, true));
}
__device__ __forceinline__ float rowsum16(float v) {
    v += ror16<8>(v); v += ror16<4>(v); v += ror16<2>(v); v += ror16<1>(v);
    return v;
}

__global__ __launch_bounds__(512, 1) void lstm_persist(
    const float* __restrict__ x, const int* __restrict__ done,
    const float* __restrict__ h0in, const float* __restrict__ c0in,
    const float* __restrict__ w_ih, const float* __restrict__ w_hh,
    const float* __restrict__ b_ih, const float* __restrict__ b_hh,
    const float* __restrict__ Wp, const float* __restrict__ bp,
    const float* __restrict__ Wb, const float* __restrict__ bb,
    float* __restrict__ out, float* __restrict__ ws)
{
    __shared__ __align__(16) float wlds[64*2*H_];      // 128 KB weight slice
    __shared__ __align__(16) float stg[16*H_];         // 16 KB operand stage
    __shared__ __align__(16) float gates[4][16][17];   // 4.25 KB
    __shared__ float hlog[19];
    // total ~148.4 KB < 160 KB; 1 WG/CU (required for co-residency)

    const int wg   = blockIdx.x;
    const int tid  = threadIdx.x;
    const int l    = wg >> 7;            // 0: layer0 (+head duty), 1: layer1
    const int wl   = wg & 127;
    const int lane = tid & 63;
    const int w    = tid >> 6;           // wave 0..7
    const int kc   = lane & 15;          // K-chunk owner (16 floats, k = q*64+kc*4)
    const int jq   = lane >> 4;          // batch-quad owner
    const int bt   = wl >> 4, hg = wl & 15, b0 = bt*16;

    // ---- stage weights ONCE: 64 gate rows x (wi,wh) -> LDS ----
    {
        const float* WI = w_ih + (size_t)l*G4H*H_;
        const float* WH = w_hh + (size_t)l*G4H*H_;
        float4* dst = (float4*)wlds;
        #pragma unroll
        for (int k = 0; k < 16; ++k) {                  // 8192 float4 / 512 thr
            const int idx = k*512 + tid;
            const int rs = idx >> 7, rem = idx & 127;
            const int m = rem >> 6, q4 = rem & 63;
            const int r = (rs >> 4)*256 + hg*16 + (rs & 15);
            const float* src = (m ? WH : WI) + (size_t)r*H_;
            dst[idx] = ((const float4*)src)[q4];
        }
    }

    // ---- per-thread persistent state ----
    float bsum[8];
    #pragma unroll
    for (int rr = 0; rr < 8; ++rr) {
        const int rs = w*8 + rr;
        const int r  = (rs >> 4)*256 + hg*16 + (rs & 15);
        bsum[rr] = b_ih[(size_t)l*G4H + r] + b_hh[(size_t)l*G4H + r];
    }
    float4 wpr[3]; float wpb[3];         // head rows w, w+8, w+16 (L0 duty)
    if (l == 0) {
        #pragma unroll
        for (int k = 0; k < 3; ++k) {
            const int a = w + 8*k;
            if (a < 19) {
                const float* wr = (a < 18) ? (Wp + (size_t)a*H_) : Wb;
                wpr[k] = ((const float4*)wr)[lane];
                wpb[k] = (a < 18) ? bp[a] : bb[0];
            }
        }
    }
    float cr = 0.f;                      // c for my (b,h) under tid<256 mapping
    const int sb = b0 + (tid >> 5);      // batch of my staged 8-float chunk

    unsigned int* stamp = (unsigned int*)(ws + WS_CTR);
    __syncthreads();                     // weights staged

    for (int p = 0; p < 516; ++p) {
        const int t = p - l;
        const bool work   = (t >= 0 && t < T_);
        const bool dohead = (l == 0 && p >= 4);         // th = p-4 in [0,512)

        // ---- issue all sc loads up front (L3 round trips overlap) ----
        float4 hh4;
        if (dohead)
            hh4 = cload4(ws + WS_H1 + (size_t)((p-4) & 3)*B_*H_ + (size_t)wl*H_ + lane*4);
        float4 ha, hb, xa, xb;
        if (work) {
            if (t == 0) {
                const float* src = h0in + (size_t)l*B_*H_ + (size_t)b0*H_ + tid*8;
                ha = ((const float4*)src)[0]; hb = ((const float4*)src)[1];
            } else {
                const float* src = ws + (l ? WS_H1 : WS_H0) + (size_t)((t-1)&3)*B_*H_
                                 + (size_t)b0*H_ + tid*8;
                ha = cload4(src); hb = cload4(src + 4);
            }
            if (l == 1) {
                const float* sx = ws + WS_H0 + (size_t)(t&3)*B_*H_ + (size_t)b0*H_ + tid*8;
                xa = cload4(sx); xb = cload4(sx + 4);
            }
        }

        // ---- head for th = p-4 (L0 WGs; h1 written >=3 phases ago) ----
        if (dohead) {
            const int th = p - 4;
            #pragma unroll
            for (int k = 0; k < 3; ++k) {
                const int a = w + 8*k;
                if (a < 19) {
                    float s = wpr[k].x*hh4.x + wpr[k].y*hh4.y + wpr[k].z*hh4.z + wpr[k].w*hh4.w;
                    s += __shfl_xor(s, 1);  s += __shfl_xor(s, 2);  s += __shfl_xor(s, 4);
                    s += __shfl_xor(s, 8);  s += __shfl_xor(s, 16); s += __shfl_xor(s, 32);
                    if (lane == 0) {
                        float v = s + wpb[k];
                        hlog[a] = v;
                        if (a < 18) out[((size_t)th*B_ + wl)*A_ + a] = v;
                        else        out[OUT_BASE + th*B_ + wl] = v;
                    }
                }
            }
        }

        // ---- gate FMA: accumulator-major, two K-sections ----
        const float4* s4 = (const float4*)stg;
        if (work) {
            const float nd = done[t*B_ + sb] ? 0.f : 1.f;
            ha.x *= nd; ha.y *= nd; ha.z *= nd; ha.w *= nd;
            hb.x *= nd; hb.y *= nd; hb.z *= nd; hb.w *= nd;

            float acc[8][4];
            #pragma unroll
            for (int rr = 0; rr < 8; ++rr)
                #pragma unroll
                for (int jj = 0; jj < 4; ++jj) acc[rr][jj] = 0.f;

            const float4* wl4 = (const float4*)wlds;

            // -- Section A: x contribution (Wi rows) --
            if (l == 1) {
                ((float4*)stg)[tid*2]     = xa;
                ((float4*)stg)[tid*2 + 1] = xb;
                __syncthreads();
            }
            const float4* xb0 = (const float4*)(x + ((size_t)t*B_ + b0)*H_);
            #pragma unroll
            for (int q = 0; q < 4; ++q) {
                float4 xf[4];
                #pragma unroll
                for (int jj = 0; jj < 4; ++jj)
                    xf[jj] = (l == 1) ? s4[(jq*4 + jj)*64 + q*16 + kc]
                                      : xb0[(size_t)(jq*4 + jj)*64 + q*16 + kc];
                #pragma unroll
                for (int rr = 0; rr < 8; ++rr) {
                    const float4 wv = wl4[(w*8 + rr)*128 + q*16 + kc];
                    acc[rr][0] += wv.x*xf[0].x + wv.y*xf[0].y + wv.z*xf[0].z + wv.w*xf[0].w;
                    acc[rr][1] += wv.x*xf[1].x + wv.y*xf[1].y + wv.z*xf[1].z + wv.w*xf[1].w;
                    acc[rr][2] += wv.x*xf[2].x + wv.y*xf[2].y + wv.z*xf[2].z + wv.w*xf[2].w;
                    acc[rr][3] += wv.x*xf[3].x + wv.y*xf[3].y + wv.z*xf[3].z + wv.w*xf[3].w;
                }
            }
            if (l == 1) __syncthreads();     // WAR: x reads done before h staging

            // -- Section B: h contribution (Wh rows), same stg buffer --
            ((float4*)stg)[tid*2]     = ha;
            ((float4*)stg)[tid*2 + 1] = hb;
            __syncthreads();
            #pragma unroll
            for (int q = 0; q < 4; ++q) {
                float4 hf[4];
                #pragma unroll
                for (int jj = 0; jj < 4; ++jj)
                    hf[jj] = s4[(jq*4 + jj)*64 + q*16 + kc];
                #pragma unroll
                for (int rr = 0; rr < 8; ++rr) {
                    const float4 wv = wl4[(w*8 + rr)*128 + 64 + q*16 + kc];
                    acc[rr][0] += wv.x*hf[0].x + wv.y*hf[0].y + wv.z*hf[0].z + wv.w*hf[0].w;
                    acc[rr][1] += wv.x*hf[1].x + wv.y*hf[1].y + wv.z*hf[1].z + wv.w*hf[1].w;
                    acc[rr][2] += wv.x*hf[2].x + wv.y*hf[2].y + wv.z*hf[2].z + wv.w*hf[2].w;
                    acc[rr][3] += wv.x*hf[3].x + wv.y*hf[3].y + wv.z*hf[3].z + wv.w*hf[3].w;
                }
            }

            // -- rowsum + gate write --
            #pragma unroll
            for (int rr = 0; rr < 8; ++rr) {
                const int rs = w*8 + rr;
                const int g  = rs >> 4, ri = rs & 15;
                const float a0 = rowsum16(acc[rr][0]);
                const float a1 = rowsum16(acc[rr][1]);
                const float a2 = rowsum16(acc[rr][2]);
                const float a3 = rowsum16(acc[rr][3]);
                const float v = (kc == 0) ? a0 : (kc == 1) ? a1
                              : (kc == 2) ? a2 : a3;
                if (kc < 4)
                    gates[g][ri][jq*4 + kc] = v + bsum[rr];
            }
        }

        __syncthreads();          // gates ready; also orders hlog for argmax

        // ---- cell update: tid<256, consecutive h -> 64B-coalesced swaps ----
        if (work && tid < 256) {
            const int j = tid >> 4, hi = tid & 15;
            const int b = b0 + j, h = hg*16 + hi;
            const float nd = done[t*B_ + b] ? 0.f : 1.f;
            if (t == 0) cr = c0in[(size_t)l*B_*H_ + b*H_ + h];
            const float cp = cr * nd;
            const float gi = gates[0][hi][j], gf = gates[1][hi][j];
            const float gv = gates[2][hi][j], go = gates[3][hi][j];
            const float ii = 1.f/(1.f + expf(-gi));
            const float ff = 1.f/(1.f + expf(-gf));
            const float gt = tanhf(gv);
            const float oo = 1.f/(1.f + expf(-go));
            const float cl = ff*cp + ii*gt;
            cr = cl;
            if (t == T_-1)
                cswap(ws + (l ? WS_C1 : WS_C0) + (size_t)b*H_ + h, cl);
            float* hout = ws + (l ? WS_H1 : WS_H0) + (size_t)(t&3)*B_*H_;
            cswap(hout + (size_t)b*H_ + h, oo*tanhf(cl));
        }

        // ---- argmax (hlog complete; ordered by the sync above) ----
        if (dohead && tid == 0) {
            const int th = p - 4;
            float best = hlog[0]; int bi = 0;
            #pragma unroll
            for (int a = 1; a < A_; ++a) { float v = hlog[a]; if (v > best) { best = v; bi = a; } }
            out[OUT_ACT + th*B_ + wl] = (float)bi;       // strict > = first-max, matches np
        }

        // ---- final state copy (L1, p=513: polls guarantee L0>=513, L1>=513) ----
        if (l == 1 && p == 513 && tid < 256) {
            const int idx = wl*H_ + tid;
            out[OUT_HT + idx]         = cload(ws + WS_H0 + 3*B_*H_ + idx);   // h0(511) slot 3
            out[OUT_HT + B_*H_ + idx] = cload(ws + WS_H1 + 3*B_*H_ + idx);   // h1(511) slot 3
            out[OUT_CT + idx]         = cload(ws + WS_C0 + idx);
            out[OUT_CT + B_*H_ + idx] = cload(ws + WS_C1 + idx);
        }

        // ---- decoupled cluster barrier ----
        if (p < 515) {
            asm volatile("s_waitcnt vmcnt(0)" ::: "memory");   // swaps acked at L3
            __syncthreads();
            if (tid == 0)
                __hip_atomic_store(stamp + wg, (unsigned)(p + 1),
                                   __ATOMIC_RELAXED, __HIP_MEMORY_SCOPE_SYSTEM);
            if (tid < 32) {
                const bool own = (tid < 16);
                const int  i   = tid & 15;
                const int  cell = (own ? l : (1 - l))*128 + bt*16 + i;
                // L0: own >= p+1, L1 (other) >= p-1 (lag-2). L1: both >= p+1.
                const int tgt = own ? (p + 1) : ((l == 0) ? (p - 1) : (p + 1));
                if (tgt > 0)
                    while (__hip_atomic_load(stamp + cell, __ATOMIC_RELAXED,
                                             __HIP_MEMORY_SCOPE_SYSTEM) < (unsigned)tgt)
                        __builtin_amdgcn_s_sleep(1);
            }
            __syncthreads();
        }
    }
}

extern "C" void kernel_launch(void* const* d_in, const int* in_sizes, int n_in,
                              void* d_out, int out_size, void* d_ws, size_t ws_size,
                              hipStream_t stream)
{
    const float* x    = (const float*)d_in[0];
    const int*   done = (const int*)  d_in[1];
    const float* h0   = (const float*)d_in[2];
    const float* c0   = (const float*)d_in[3];
    const float* w_ih = (const float*)d_in[4];
    const float* w_hh = (const float*)d_in[5];
    const float* b_ih = (const float*)d_in[6];
    const float* b_hh = (const float*)d_in[7];
    const float* Wp   = (const float*)d_in[8];
    const float* bp   = (const float*)d_in[9];
    const float* Wb   = (const float*)d_in[10];
    const float* bb   = (const float*)d_in[11];
    float* out = (float*)d_out;
    float* ws  = (float*)d_ws;    // 1.31 MB state + 1 KB stamp cells

    // zero the 256 stamp cells (captured node, re-runs every replay)
    hipMemsetAsync((char*)d_ws + (size_t)WS_CTR*sizeof(float), 0, 1024, stream);

    lstm_persist<<<dim3(256), dim3(512), 0, stream>>>(
        x, done, h0, c0, w_ih, w_hh, b_ih, b_hh, Wp, bp, Wb, bb, out, ws);
}

// Round 14
// 7241.721 us; speedup vs baseline: 3.2839x; 3.2839x over previous
//
#include <hip/hip_runtime.h>
#include <math.h>

#define T_  512
#define B_  128
#define H_  256
#define A_  18
#define G4H 1024
#define TB_ (T_*B_)

// d_out layout (floats): [logits T*B*A][baseline T*B][action T*B][hT 2*B*H][cT 2*B*H]
#define OUT_BASE  (TB_*A_)
#define OUT_ACT   (OUT_BASE + TB_)
#define OUT_HT    (OUT_ACT + TB_)
#define OUT_CT    (OUT_HT + 2*B_*H_)

// workspace (floats): PARITY-4 h per layer (slot = t&3), private c per layer,
// then 256 uint phase-stamp cells (one per WG, memset once per replay). 1.31 MB.
#define WS_H0  0                  // [4][B][H]
#define WS_H1  (4*B_*H_)          // [4][B][H]
#define WS_C0  (8*B_*H_)
#define WS_C1  (9*B_*H_)
#define WS_CTR (10*B_*H_)

// SINGLE-DISPATCH DECOUPLED-LAYER PIPELINE, v14 = v11 + two-section partial sums.
// v13 post-mortem: acc[8][4] held live across staging barriers -> compiler
// allocated it in SCRATCH (69 GB/dispatch of spill traffic, VALUBusy 12%).
// Hard rule learned (v12+v13): nothing beyond v11's proven 64-reg fragment set
// may live across a barrier. v14 gets the DS-read savings within that rule:
//   Section A: read x-frags (64 regs, live only inside A), per row read Wi
//     ONCE, rowsum, gates[slot] = xdot + bsum  (partial).
//   Section B: stage h (same stg buffer, WAR barrier), read h-frags (64 regs,
//     live only inside B), per row read Wh ONCE, gates[slot] += hdot.
// gates RMW is thread-private (same lane owns the slot in both passes) and
// barrier-ordered. Accumulators are per-row transients. DS instr/thread
// ~174 -> ~126 (weight re-read eliminated). Everything else verbatim v11:
// decoupled parity-4 pipeline, returning-swap cross-WG writes (acked at the
// L3 coherence point before vmcnt(0) clears), store-stamp arrival, relaxed
// system-scope polls, DPP rowsum, head-on-L0, coalesced tid<256 cell update.

__device__ __forceinline__ float cload(const float* p) {
    return __hip_atomic_load((float*)p, __ATOMIC_RELAXED, __HIP_MEMORY_SCOPE_SYSTEM);
}
__device__ __forceinline__ float4 cload4(const float* p) {   // 16B-aligned
    union { unsigned long long u[2]; float4 f; } r;
    r.u[0] = __hip_atomic_load((const unsigned long long*)p,
                               __ATOMIC_RELAXED, __HIP_MEMORY_SCOPE_SYSTEM);
    r.u[1] = __hip_atomic_load((const unsigned long long*)(p + 2),
                               __ATOMIC_RELAXED, __HIP_MEMORY_SCOPE_SYSTEM);
    return r.f;
}
// ordered data write: atomic exchange, returning form forced by asm sink
__device__ __forceinline__ void cswap(float* p, float v) {
    float old = __hip_atomic_exchange(p, v, __ATOMIC_RELAXED, __HIP_MEMORY_SCOPE_SYSTEM);
    asm volatile("" :: "v"(old));
}
// DPP row_ror (within 16-lane rows); 4 rotation-adds = full 16-lane sum on VALU
template<int N>
__device__ __forceinline__ float ror16(float v) {
    return __int_as_float(__builtin_amdgcn_update_dpp(
        0, __float_as_int(v), 0x120 | N, 0xF, 0xF, true));
}
__device__ __forceinline__ float rowsum16(float v) {
    v += ror16<8>(v); v += ror16<4>(v); v += ror16<2>(v); v += ror16<1>(v);
    return v;
}

__global__ __launch_bounds__(512, 1) void lstm_persist(
    const float* __restrict__ x, const int* __restrict__ done,
    const float* __restrict__ h0in, const float* __restrict__ c0in,
    const float* __restrict__ w_ih, const float* __restrict__ w_hh,
    const float* __restrict__ b_ih, const float* __restrict__ b_hh,
    const float* __restrict__ Wp, const float* __restrict__ bp,
    const float* __restrict__ Wb, const float* __restrict__ bb,
    float* __restrict__ out, float* __restrict__ ws)
{
    __shared__ __align__(16) float wlds[64*2*H_];      // 128 KB weight slice
    __shared__ __align__(16) float stg[16*H_];         // 16 KB operand stage
    __shared__ __align__(16) float gates[4][16][17];   // 4.25 KB
    __shared__ float hlog[19];
    // total ~148.4 KB < 160 KB; 1 WG/CU (required for co-residency)

    const int wg   = blockIdx.x;
    const int tid  = threadIdx.x;
    const int l    = wg >> 7;            // 0: layer0 (+head duty), 1: layer1
    const int wl   = wg & 127;
    const int lane = tid & 63;
    const int w    = tid >> 6;           // wave 0..7
    const int kc   = lane & 15;          // K-chunk owner (16 floats, k = q*64+kc*4)
    const int jq   = lane >> 4;          // batch-quad owner
    const int bt   = wl >> 4, hg = wl & 15, b0 = bt*16;

    // ---- stage weights ONCE: 64 gate rows x (wi,wh) -> LDS ----
    {
        const float* WI = w_ih + (size_t)l*G4H*H_;
        const float* WH = w_hh + (size_t)l*G4H*H_;
        float4* dst = (float4*)wlds;
        #pragma unroll
        for (int k = 0; k < 16; ++k) {                  // 8192 float4 / 512 thr
            const int idx = k*512 + tid;
            const int rs = idx >> 7, rem = idx & 127;
            const int m = rem >> 6, q4 = rem & 63;
            const int r = (rs >> 4)*256 + hg*16 + (rs & 15);
            const float* src = (m ? WH : WI) + (size_t)r*H_;
            dst[idx] = ((const float4*)src)[q4];
        }
    }

    // ---- per-thread persistent state ----
    float bsum[8];
    #pragma unroll
    for (int rr = 0; rr < 8; ++rr) {
        const int rs = w*8 + rr;
        const int r  = (rs >> 4)*256 + hg*16 + (rs & 15);
        bsum[rr] = b_ih[(size_t)l*G4H + r] + b_hh[(size_t)l*G4H + r];
    }
    float4 wpr[3]; float wpb[3];         // head rows w, w+8, w+16 (L0 duty)
    if (l == 0) {
        #pragma unroll
        for (int k = 0; k < 3; ++k) {
            const int a = w + 8*k;
            if (a < 19) {
                const float* wr = (a < 18) ? (Wp + (size_t)a*H_) : Wb;
                wpr[k] = ((const float4*)wr)[lane];
                wpb[k] = (a < 18) ? bp[a] : bb[0];
            }
        }
    }
    float cr = 0.f;                      // c for my (b,h) under tid<256 mapping
    const int sb = b0 + (tid >> 5);      // batch of my staged 8-float chunk

    unsigned int* stamp = (unsigned int*)(ws + WS_CTR);
    __syncthreads();                     // weights staged

    for (int p = 0; p < 516; ++p) {
        const int t = p - l;
        const bool work   = (t >= 0 && t < T_);
        const bool dohead = (l == 0 && p >= 4);         // th = p-4 in [0,512)

        // ---- issue all sc loads up front (L3 round trips overlap) ----
        float4 hh4;
        if (dohead)
            hh4 = cload4(ws + WS_H1 + (size_t)((p-4) & 3)*B_*H_ + (size_t)wl*H_ + lane*4);
        float4 ha, hb, xa, xb;
        if (work) {
            if (t == 0) {
                const float* src = h0in + (size_t)l*B_*H_ + (size_t)b0*H_ + tid*8;
                ha = ((const float4*)src)[0]; hb = ((const float4*)src)[1];
            } else {
                const float* src = ws + (l ? WS_H1 : WS_H0) + (size_t)((t-1)&3)*B_*H_
                                 + (size_t)b0*H_ + tid*8;
                ha = cload4(src); hb = cload4(src + 4);
            }
            if (l == 1) {
                const float* sx = ws + WS_H0 + (size_t)(t&3)*B_*H_ + (size_t)b0*H_ + tid*8;
                xa = cload4(sx); xb = cload4(sx + 4);
            }
        }

        // ---- head for th = p-4 (L0 WGs; h1 written >=3 phases ago) ----
        if (dohead) {
            const int th = p - 4;
            #pragma unroll
            for (int k = 0; k < 3; ++k) {
                const int a = w + 8*k;
                if (a < 19) {
                    float s = wpr[k].x*hh4.x + wpr[k].y*hh4.y + wpr[k].z*hh4.z + wpr[k].w*hh4.w;
                    s += __shfl_xor(s, 1);  s += __shfl_xor(s, 2);  s += __shfl_xor(s, 4);
                    s += __shfl_xor(s, 8);  s += __shfl_xor(s, 16); s += __shfl_xor(s, 32);
                    if (lane == 0) {
                        float v = s + wpb[k];
                        hlog[a] = v;
                        if (a < 18) out[((size_t)th*B_ + wl)*A_ + a] = v;
                        else        out[OUT_BASE + th*B_ + wl] = v;
                    }
                }
            }
        }

        // ---- gate FMA: two sections, partial sums into gates LDS ----
        const float4* s4 = (const float4*)stg;
        if (work) {
            const float nd = done[t*B_ + sb] ? 0.f : 1.f;
            ha.x *= nd; ha.y *= nd; ha.z *= nd; ha.w *= nd;
            hb.x *= nd; hb.y *= nd; hb.z *= nd; hb.w *= nd;
            const float4* wl4 = (const float4*)wlds;

            // -- Section A: x·Wi -> gates = partial + bias --
            {
                float4 xr4[4][4];
                if (l == 1) {
                    ((float4*)stg)[tid*2]     = xa;
                    ((float4*)stg)[tid*2 + 1] = xb;
                    __syncthreads();
                    #pragma unroll
                    for (int jj = 0; jj < 4; ++jj)
                        #pragma unroll
                        for (int q = 0; q < 4; ++q)
                            xr4[jj][q] = s4[(jq*4 + jj)*64 + q*16 + kc];
                    __syncthreads();                    // WAR: stg free for h
                } else {
                    const float4* xb0 = (const float4*)(x + ((size_t)t*B_ + b0)*H_);
                    #pragma unroll
                    for (int jj = 0; jj < 4; ++jj)
                        #pragma unroll
                        for (int q = 0; q < 4; ++q)
                            xr4[jj][q] = xb0[(size_t)(jq*4 + jj)*64 + q*16 + kc];
                }
                #pragma unroll 2
                for (int rr = 0; rr < 8; ++rr) {
                    const int rs = w*8 + rr;
                    const int g  = rs >> 4, ri = rs & 15;
                    const int wb4 = rs*128;
                    float4 wiv[4];
                    #pragma unroll
                    for (int q = 0; q < 4; ++q) wiv[q] = wl4[wb4 + q*16 + kc];
                    float acc0 = 0.f, acc1 = 0.f, acc2 = 0.f, acc3 = 0.f;
                    #pragma unroll
                    for (int q = 0; q < 4; ++q) {
                        acc0 += wiv[q].x*xr4[0][q].x + wiv[q].y*xr4[0][q].y
                              + wiv[q].z*xr4[0][q].z + wiv[q].w*xr4[0][q].w;
                        acc1 += wiv[q].x*xr4[1][q].x + wiv[q].y*xr4[1][q].y
                              + wiv[q].z*xr4[1][q].z + wiv[q].w*xr4[1][q].w;
                        acc2 += wiv[q].x*xr4[2][q].x + wiv[q].y*xr4[2][q].y
                              + wiv[q].z*xr4[2][q].z + wiv[q].w*xr4[2][q].w;
                        acc3 += wiv[q].x*xr4[3][q].x + wiv[q].y*xr4[3][q].y
                              + wiv[q].z*xr4[3][q].z + wiv[q].w*xr4[3][q].w;
                    }
                    acc0 = rowsum16(acc0); acc1 = rowsum16(acc1);
                    acc2 = rowsum16(acc2); acc3 = rowsum16(acc3);
                    const float v = (kc == 0) ? acc0 : (kc == 1) ? acc1
                                  : (kc == 2) ? acc2 : acc3;
                    if (kc < 4)
                        gates[g][ri][jq*4 + kc] = v + bsum[rr];
                }
            }

            // -- Section B: h·Wh -> gates += partial --
            {
                ((float4*)stg)[tid*2]     = ha;
                ((float4*)stg)[tid*2 + 1] = hb;
                __syncthreads();
                float4 hr4[4][4];
                #pragma unroll
                for (int jj = 0; jj < 4; ++jj)
                    #pragma unroll
                    for (int q = 0; q < 4; ++q)
                        hr4[jj][q] = s4[(jq*4 + jj)*64 + q*16 + kc];
                #pragma unroll 2
                for (int rr = 0; rr < 8; ++rr) {
                    const int rs = w*8 + rr;
                    const int g  = rs >> 4, ri = rs & 15;
                    const int wb4 = rs*128;
                    float4 whv[4];
                    #pragma unroll
                    for (int q = 0; q < 4; ++q) whv[q] = wl4[wb4 + 64 + q*16 + kc];
                    float acc0 = 0.f, acc1 = 0.f, acc2 = 0.f, acc3 = 0.f;
                    #pragma unroll
                    for (int q = 0; q < 4; ++q) {
                        acc0 += whv[q].x*hr4[0][q].x + whv[q].y*hr4[0][q].y
                              + whv[q].z*hr4[0][q].z + whv[q].w*hr4[0][q].w;
                        acc1 += whv[q].x*hr4[1][q].x + whv[q].y*hr4[1][q].y
                              + whv[q].z*hr4[1][q].z + whv[q].w*hr4[1][q].w;
                        acc2 += whv[q].x*hr4[2][q].x + whv[q].y*hr4[2][q].y
                              + whv[q].z*hr4[2][q].z + whv[q].w*hr4[2][q].w;
                        acc3 += whv[q].x*hr4[3][q].x + whv[q].y*hr4[3][q].y
                              + whv[q].z*hr4[3][q].z + whv[q].w*hr4[3][q].w;
                    }
                    acc0 = rowsum16(acc0); acc1 = rowsum16(acc1);
                    acc2 = rowsum16(acc2); acc3 = rowsum16(acc3);
                    const float v = (kc == 0) ? acc0 : (kc == 1) ? acc1
                                  : (kc == 2) ? acc2 : acc3;
                    if (kc < 4)
                        gates[g][ri][jq*4 + kc] += v;    // thread-private RMW
                }
            }
        }

        __syncthreads();          // gates ready; also orders hlog for argmax

        // ---- cell update: tid<256, consecutive h -> 64B-coalesced swaps ----
        if (work && tid < 256) {
            const int j = tid >> 4, hi = tid & 15;
            const int b = b0 + j, h = hg*16 + hi;
            const float nd = done[t*B_ + b] ? 0.f : 1.f;
            if (t == 0) cr = c0in[(size_t)l*B_*H_ + b*H_ + h];
            const float cp = cr * nd;
            const float gi = gates[0][hi][j], gf = gates[1][hi][j];
            const float gv = gates[2][hi][j], go = gates[3][hi][j];
            const float ii = 1.f/(1.f + expf(-gi));
            const float ff = 1.f/(1.f + expf(-gf));
            const float gt = tanhf(gv);
            const float oo = 1.f/(1.f + expf(-go));
            const float cl = ff*cp + ii*gt;
            cr = cl;
            if (t == T_-1)
                cswap(ws + (l ? WS_C1 : WS_C0) + (size_t)b*H_ + h, cl);
            float* hout = ws + (l ? WS_H1 : WS_H0) + (size_t)(t&3)*B_*H_;
            cswap(hout + (size_t)b*H_ + h, oo*tanhf(cl));
        }

        // ---- argmax (hlog complete; ordered by the sync above) ----
        if (dohead && tid == 0) {
            const int th = p - 4;
            float best = hlog[0]; int bi = 0;
            #pragma unroll
            for (int a = 1; a < A_; ++a) { float v = hlog[a]; if (v > best) { best = v; bi = a; } }
            out[OUT_ACT + th*B_ + wl] = (float)bi;       // strict > = first-max, matches np
        }

        // ---- final state copy (L1, p=513: polls guarantee L0>=513, L1>=513) ----
        if (l == 1 && p == 513 && tid < 256) {
            const int idx = wl*H_ + tid;
            out[OUT_HT + idx]         = cload(ws + WS_H0 + 3*B_*H_ + idx);   // h0(511) slot 3
            out[OUT_HT + B_*H_ + idx] = cload(ws + WS_H1 + 3*B_*H_ + idx);   // h1(511) slot 3
            out[OUT_CT + idx]         = cload(ws + WS_C0 + idx);
            out[OUT_CT + B_*H_ + idx] = cload(ws + WS_C1 + idx);
        }

        // ---- decoupled cluster barrier ----
        if (p < 515) {
            asm volatile("s_waitcnt vmcnt(0)" ::: "memory");   // swaps acked at L3
            __syncthreads();
            if (tid == 0)
                __hip_atomic_store(stamp + wg, (unsigned)(p + 1),
                                   __ATOMIC_RELAXED, __HIP_MEMORY_SCOPE_SYSTEM);
            if (tid < 32) {
                const bool own = (tid < 16);
                const int  i   = tid & 15;
                const int  cell = (own ? l : (1 - l))*128 + bt*16 + i;
                // L0: own >= p+1, L1 (other) >= p-1 (lag-2). L1: both >= p+1.
                const int tgt = own ? (p + 1) : ((l == 0) ? (p - 1) : (p + 1));
                if (tgt > 0)
                    while (__hip_atomic_load(stamp + cell, __ATOMIC_RELAXED,
                                             __HIP_MEMORY_SCOPE_SYSTEM) < (unsigned)tgt)
                        __builtin_amdgcn_s_sleep(1);
            }
            __syncthreads();
        }
    }
}

extern "C" void kernel_launch(void* const* d_in, const int* in_sizes, int n_in,
                              void* d_out, int out_size, void* d_ws, size_t ws_size,
                              hipStream_t stream)
{
    const float* x    = (const float*)d_in[0];
    const int*   done = (const int*)  d_in[1];
    const float* h0   = (const float*)d_in[2];
    const float* c0   = (const float*)d_in[3];
    const float* w_ih = (const float*)d_in[4];
    const float* w_hh = (const float*)d_in[5];
    const float* b_ih = (const float*)d_in[6];
    const float* b_hh = (const float*)d_in[7];
    const float* Wp   = (const float*)d_in[8];
    const float* bp   = (const float*)d_in[9];
    const float* Wb   = (const float*)d_in[10];
    const float* bb   = (const float*)d_in[11];
    float* out = (float*)d_out;
    float* ws  = (float*)d_ws;    // 1.31 MB state + 1 KB stamp cells

    // zero the 256 stamp cells (captured node, re-runs every replay)
    hipMemsetAsync((char*)d_ws + (size_t)WS_CTR*sizeof(float), 0, 1024, stream);

    lstm_persist<<<dim3(256), dim3(512), 0, stream>>>(
        x, done, h0, c0, w_ih, w_hh, b_ih, b_hh, Wp, bp, Wb, bb, out, ws);
}

// Round 15
// 6539.398 us; speedup vs baseline: 3.6366x; 1.1074x over previous
//
#include <hip/hip_runtime.h>
#include <math.h>

#define T_  512
#define B_  128
#define H_  256
#define A_  18
#define G4H 1024
#define TB_ (T_*B_)

// d_out layout (floats): [logits T*B*A][baseline T*B][action T*B][hT 2*B*H][cT 2*B*H]
#define OUT_BASE  (TB_*A_)
#define OUT_ACT   (OUT_BASE + TB_)
#define OUT_HT    (OUT_ACT + TB_)
#define OUT_CT    (OUT_HT + 2*B_*H_)

// workspace (floats): PARITY-4 h per layer (slot = t&3), private c per layer,
// then 256 uint phase-stamp cells (one per WG, memset once per replay). 1.31 MB.
#define WS_H0  0                  // [4][B][H]
#define WS_H1  (4*B_*H_)          // [4][B][H]
#define WS_C0  (8*B_*H_)
#define WS_C1  (9*B_*H_)
#define WS_CTR (10*B_*H_)

// SINGLE-DISPATCH DECOUPLED-LAYER PIPELINE, v15.
// v12-v14 post-mortem: every sub-128-VGPR scheme to cut DS reads failed
// (remat, pin-spill, scratch-acc). Root cause found: LLVM's allocator targets
// its DEFAULT 4 waves/EU occupancy -> 128-VGPR cap -- but our 148 KB LDS
// already limits the CU to 1 WG = 8 waves = 2 waves/EU. The occupancy the
// compiler protects cannot exist. Fix: amdgpu_waves_per_eu(2,2) clamps the
// target to exactly 2 waves/EU -> 256-VGPR budget. v12's single-pass body
// (xr4+hr4 = 128 fragment regs live, weights read ONCE per row) then fits
// with no pins and no remat: DS reads/thread ~170 (v11) -> ~100.
// Failure mode is safe: if the attribute is ignored the allocator remats
// (v9-like, ~6.6 ms), not a scratch blowup (pins removed).
// Sync skeleton verbatim v6-v14 (proven): decoupled parity-4 pipeline,
// returning-swap cross-WG writes (acked at the L3 coherence point before
// vmcnt(0) clears), store-stamp arrival, relaxed system-scope polls,
// DPP rowsum, head-on-L0, coalesced tid<256 cell update, no fences.

__device__ __forceinline__ float cload(const float* p) {
    return __hip_atomic_load((float*)p, __ATOMIC_RELAXED, __HIP_MEMORY_SCOPE_SYSTEM);
}
__device__ __forceinline__ float4 cload4(const float* p) {   // 16B-aligned
    union { unsigned long long u[2]; float4 f; } r;
    r.u[0] = __hip_atomic_load((const unsigned long long*)p,
                               __ATOMIC_RELAXED, __HIP_MEMORY_SCOPE_SYSTEM);
    r.u[1] = __hip_atomic_load((const unsigned long long*)(p + 2),
                               __ATOMIC_RELAXED, __HIP_MEMORY_SCOPE_SYSTEM);
    return r.f;
}
// ordered data write: atomic exchange, returning form forced by asm sink
__device__ __forceinline__ void cswap(float* p, float v) {
    float old = __hip_atomic_exchange(p, v, __ATOMIC_RELAXED, __HIP_MEMORY_SCOPE_SYSTEM);
    asm volatile("" :: "v"(old));
}
// DPP row_ror (within 16-lane rows); 4 rotation-adds = full 16-lane sum on VALU
template<int N>
__device__ __forceinline__ float ror16(float v) {
    return __int_as_float(__builtin_amdgcn_update_dpp(
        0, __float_as_int(v), 0x120 | N, 0xF, 0xF, true));
}
__device__ __forceinline__ float rowsum16(float v) {
    v += ror16<8>(v); v += ror16<4>(v); v += ror16<2>(v); v += ror16<1>(v);
    return v;
}

__global__ __attribute__((amdgpu_waves_per_eu(2, 2))) __launch_bounds__(512)
void lstm_persist(
    const float* __restrict__ x, const int* __restrict__ done,
    const float* __restrict__ h0in, const float* __restrict__ c0in,
    const float* __restrict__ w_ih, const float* __restrict__ w_hh,
    const float* __restrict__ b_ih, const float* __restrict__ b_hh,
    const float* __restrict__ Wp, const float* __restrict__ bp,
    const float* __restrict__ Wb, const float* __restrict__ bb,
    float* __restrict__ out, float* __restrict__ ws)
{
    __shared__ __align__(16) float wlds[64*2*H_];      // 128 KB weight slice
    __shared__ __align__(16) float stg[16*H_];         // 16 KB activation stage
    __shared__ __align__(16) float gates[4][16][17];   // 4.25 KB
    __shared__ float hlog[19];
    // total ~148.4 KB < 160 KB; 1 WG/CU (required for co-residency)

    const int wg   = blockIdx.x;
    const int tid  = threadIdx.x;
    const int l    = wg >> 7;            // 0: layer0 (+head duty), 1: layer1
    const int wl   = wg & 127;
    const int lane = tid & 63;
    const int w    = tid >> 6;           // wave 0..7
    const int kc   = lane & 15;          // K-chunk owner (16 floats, k = q*64+kc*4)
    const int jq   = lane >> 4;          // batch-quad owner
    const int bt   = wl >> 4, hg = wl & 15, b0 = bt*16;

    // ---- stage weights ONCE: 64 gate rows x (wi,wh) -> LDS ----
    {
        const float* WI = w_ih + (size_t)l*G4H*H_;
        const float* WH = w_hh + (size_t)l*G4H*H_;
        float4* dst = (float4*)wlds;
        #pragma unroll
        for (int k = 0; k < 16; ++k) {                  // 8192 float4 / 512 thr
            const int idx = k*512 + tid;
            const int rs = idx >> 7, rem = idx & 127;
            const int m = rem >> 6, q4 = rem & 63;
            const int r = (rs >> 4)*256 + hg*16 + (rs & 15);
            const float* src = (m ? WH : WI) + (size_t)r*H_;
            dst[idx] = ((const float4*)src)[q4];
        }
    }

    // ---- per-thread persistent state ----
    float bsum[8];
    #pragma unroll
    for (int rr = 0; rr < 8; ++rr) {
        const int rs = w*8 + rr;
        const int r  = (rs >> 4)*256 + hg*16 + (rs & 15);
        bsum[rr] = b_ih[(size_t)l*G4H + r] + b_hh[(size_t)l*G4H + r];
    }
    float4 wpr[3]; float wpb[3];         // head rows w, w+8, w+16 (L0 duty)
    if (l == 0) {
        #pragma unroll
        for (int k = 0; k < 3; ++k) {
            const int a = w + 8*k;
            if (a < 19) {
                const float* wr = (a < 18) ? (Wp + (size_t)a*H_) : Wb;
                wpr[k] = ((const float4*)wr)[lane];
                wpb[k] = (a < 18) ? bp[a] : bb[0];
            }
        }
    }
    float cr = 0.f;                      // c for my (b,h) under tid<256 mapping
    const int sb = b0 + (tid >> 5);      // batch of my staged 8-float chunk

    unsigned int* stamp = (unsigned int*)(ws + WS_CTR);
    __syncthreads();                     // weights staged

    for (int p = 0; p < 516; ++p) {
        const int t = p - l;
        const bool work   = (t >= 0 && t < T_);
        const bool dohead = (l == 0 && p >= 4);         // th = p-4 in [0,512)

        // ---- issue all sc loads up front (L3 round trips overlap) ----
        float4 hh4;
        if (dohead)
            hh4 = cload4(ws + WS_H1 + (size_t)((p-4) & 3)*B_*H_ + (size_t)wl*H_ + lane*4);
        float4 ha, hb, xa, xb;
        if (work) {
            if (t == 0) {
                const float* src = h0in + (size_t)l*B_*H_ + (size_t)b0*H_ + tid*8;
                ha = ((const float4*)src)[0]; hb = ((const float4*)src)[1];
            } else {
                const float* src = ws + (l ? WS_H1 : WS_H0) + (size_t)((t-1)&3)*B_*H_
                                 + (size_t)b0*H_ + tid*8;
                ha = cload4(src); hb = cload4(src + 4);
            }
            if (l == 1) {
                const float* sx = ws + WS_H0 + (size_t)(t&3)*B_*H_ + (size_t)b0*H_ + tid*8;
                xa = cload4(sx); xb = cload4(sx + 4);
            }
        }

        // ---- head for th = p-4 (L0 WGs; h1 written >=3 phases ago) ----
        if (dohead) {
            const int th = p - 4;
            #pragma unroll
            for (int k = 0; k < 3; ++k) {
                const int a = w + 8*k;
                if (a < 19) {
                    float s = wpr[k].x*hh4.x + wpr[k].y*hh4.y + wpr[k].z*hh4.z + wpr[k].w*hh4.w;
                    s += __shfl_xor(s, 1);  s += __shfl_xor(s, 2);  s += __shfl_xor(s, 4);
                    s += __shfl_xor(s, 8);  s += __shfl_xor(s, 16); s += __shfl_xor(s, 32);
                    if (lane == 0) {
                        float v = s + wpb[k];
                        hlog[a] = v;
                        if (a < 18) out[((size_t)th*B_ + wl)*A_ + a] = v;
                        else        out[OUT_BASE + th*B_ + wl] = v;
                    }
                }
            }
        }

        // ---- staging + gate FMA (single pass, full fragment set) ----
        const float4* s4 = (const float4*)stg;
        if (work) {
            const float nd = done[t*B_ + sb] ? 0.f : 1.f;
            ha.x *= nd; ha.y *= nd; ha.z *= nd; ha.w *= nd;
            hb.x *= nd; hb.y *= nd; hb.z *= nd; hb.w *= nd;

            // -- x-fragments into registers --
            float4 xr4[4][4];
            if (l == 1) {
                ((float4*)stg)[tid*2]     = xa;
                ((float4*)stg)[tid*2 + 1] = xb;
                __syncthreads();
                #pragma unroll
                for (int jj = 0; jj < 4; ++jj)
                    #pragma unroll
                    for (int q = 0; q < 4; ++q)
                        xr4[jj][q] = s4[(jq*4 + jj)*64 + q*16 + kc];
                __syncthreads();                        // all x-reads done (WAR)
            } else {
                const float4* xb0 = (const float4*)(x + ((size_t)t*B_ + b0)*H_);
                #pragma unroll
                for (int jj = 0; jj < 4; ++jj)
                    #pragma unroll
                    for (int q = 0; q < 4; ++q)
                        xr4[jj][q] = xb0[(size_t)(jq*4 + jj)*64 + q*16 + kc];
            }

            // -- stage masked h; read fragments --
            ((float4*)stg)[tid*2]     = ha;
            ((float4*)stg)[tid*2 + 1] = hb;
            __syncthreads();
            float4 hr4[4][4];
            #pragma unroll
            for (int jj = 0; jj < 4; ++jj)
                #pragma unroll
                for (int q = 0; q < 4; ++q)
                    hr4[jj][q] = s4[(jq*4 + jj)*64 + q*16 + kc];

            // -- single FMA pass: 8 rows, weights read ONCE each --
            const float4* wl4 = (const float4*)wlds;
            #pragma unroll 2
            for (int rr = 0; rr < 8; ++rr) {
                const int rs = w*8 + rr;
                const int g  = rs >> 4, ri = rs & 15;
                const int wb4 = rs*128;
                float4 wiv[4], whv[4];
                #pragma unroll
                for (int q = 0; q < 4; ++q) {
                    wiv[q] = wl4[wb4 + q*16 + kc];
                    whv[q] = wl4[wb4 + 64 + q*16 + kc];
                }
                float acc0 = 0.f, acc1 = 0.f, acc2 = 0.f, acc3 = 0.f;
                #pragma unroll
                for (int q = 0; q < 4; ++q) {
                    acc0 += wiv[q].x*xr4[0][q].x + wiv[q].y*xr4[0][q].y + wiv[q].z*xr4[0][q].z + wiv[q].w*xr4[0][q].w
                          + whv[q].x*hr4[0][q].x + whv[q].y*hr4[0][q].y + whv[q].z*hr4[0][q].z + whv[q].w*hr4[0][q].w;
                    acc1 += wiv[q].x*xr4[1][q].x + wiv[q].y*xr4[1][q].y + wiv[q].z*xr4[1][q].z + wiv[q].w*xr4[1][q].w
                          + whv[q].x*hr4[1][q].x + whv[q].y*hr4[1][q].y + whv[q].z*hr4[1][q].z + whv[q].w*hr4[1][q].w;
                    acc2 += wiv[q].x*xr4[2][q].x + wiv[q].y*xr4[2][q].y + wiv[q].z*xr4[2][q].z + wiv[q].w*xr4[2][q].w
                          + whv[q].x*hr4[2][q].x + whv[q].y*hr4[2][q].y + whv[q].z*hr4[2][q].z + whv[q].w*hr4[2][q].w;
                    acc3 += wiv[q].x*xr4[3][q].x + wiv[q].y*xr4[3][q].y + wiv[q].z*xr4[3][q].z + wiv[q].w*xr4[3][q].w
                          + whv[q].x*hr4[3][q].x + whv[q].y*hr4[3][q].y + whv[q].z*hr4[3][q].z + whv[q].w*hr4[3][q].w;
                }
                acc0 = rowsum16(acc0); acc1 = rowsum16(acc1);
                acc2 = rowsum16(acc2); acc3 = rowsum16(acc3);
                const float v = (kc == 0) ? acc0 : (kc == 1) ? acc1
                              : (kc == 2) ? acc2 : acc3;
                if (kc < 4)
                    gates[g][ri][jq*4 + kc] = v + bsum[rr];
            }
        }

        __syncthreads();          // gates ready; also orders hlog for argmax

        // ---- cell update: tid<256, consecutive h -> 64B-coalesced swaps ----
        if (work && tid < 256) {
            const int j = tid >> 4, hi = tid & 15;
            const int b = b0 + j, h = hg*16 + hi;
            const float nd = done[t*B_ + b] ? 0.f : 1.f;
            if (t == 0) cr = c0in[(size_t)l*B_*H_ + b*H_ + h];
            const float cp = cr * nd;
            const float gi = gates[0][hi][j], gf = gates[1][hi][j];
            const float gv = gates[2][hi][j], go = gates[3][hi][j];
            const float ii = 1.f/(1.f + expf(-gi));
            const float ff = 1.f/(1.f + expf(-gf));
            const float gt = tanhf(gv);
            const float oo = 1.f/(1.f + expf(-go));
            const float cl = ff*cp + ii*gt;
            cr = cl;
            if (t == T_-1)
                cswap(ws + (l ? WS_C1 : WS_C0) + (size_t)b*H_ + h, cl);
            float* hout = ws + (l ? WS_H1 : WS_H0) + (size_t)(t&3)*B_*H_;
            cswap(hout + (size_t)b*H_ + h, oo*tanhf(cl));
        }

        // ---- argmax (hlog complete; ordered by the sync above) ----
        if (dohead && tid == 0) {
            const int th = p - 4;
            float best = hlog[0]; int bi = 0;
            #pragma unroll
            for (int a = 1; a < A_; ++a) { float v = hlog[a]; if (v > best) { best = v; bi = a; } }
            out[OUT_ACT + th*B_ + wl] = (float)bi;       // strict > = first-max, matches np
        }

        // ---- final state copy (L1, p=513: polls guarantee L0>=513, L1>=513) ----
        if (l == 1 && p == 513 && tid < 256) {
            const int idx = wl*H_ + tid;
            out[OUT_HT + idx]         = cload(ws + WS_H0 + 3*B_*H_ + idx);   // h0(511) slot 3
            out[OUT_HT + B_*H_ + idx] = cload(ws + WS_H1 + 3*B_*H_ + idx);   // h1(511) slot 3
            out[OUT_CT + idx]         = cload(ws + WS_C0 + idx);
            out[OUT_CT + B_*H_ + idx] = cload(ws + WS_C1 + idx);
        }

        // ---- decoupled cluster barrier ----
        if (p < 515) {
            asm volatile("s_waitcnt vmcnt(0)" ::: "memory");   // swaps acked at L3
            __syncthreads();
            if (tid == 0)
                __hip_atomic_store(stamp + wg, (unsigned)(p + 1),
                                   __ATOMIC_RELAXED, __HIP_MEMORY_SCOPE_SYSTEM);
            if (tid < 32) {
                const bool own = (tid < 16);
                const int  i   = tid & 15;
                const int  cell = (own ? l : (1 - l))*128 + bt*16 + i;
                // L0: own >= p+1, L1 (other) >= p-1 (lag-2). L1: both >= p+1.
                const int tgt = own ? (p + 1) : ((l == 0) ? (p - 1) : (p + 1));
                if (tgt > 0)
                    while (__hip_atomic_load(stamp + cell, __ATOMIC_RELAXED,
                                             __HIP_MEMORY_SCOPE_SYSTEM) < (unsigned)tgt)
                        __builtin_amdgcn_s_sleep(1);
            }
            __syncthreads();
        }
    }
}

extern "C" void kernel_launch(void* const* d_in, const int* in_sizes, int n_in,
                              void* d_out, int out_size, void* d_ws, size_t ws_size,
                              hipStream_t stream)
{
    const float* x    = (const float*)d_in[0];
    const int*   done = (const int*)  d_in[1];
    const float* h0   = (const float*)d_in[2];
    const float* c0   = (const float*)d_in[3];
    const float* w_ih = (const float*)d_in[4];
    const float* w_hh = (const float*)d_in[5];
    const float* b_ih = (const float*)d_in[6];
    const float* b_hh = (const float*)d_in[7];
    const float* Wp   = (const float*)d_in[8];
    const float* bp   = (const float*)d_in[9];
    const float* Wb   = (const float*)d_in[10];
    const float* bb   = (const float*)d_in[11];
    float* out = (float*)d_out;
    float* ws  = (float*)d_ws;    // 1.31 MB state + 1 KB stamp cells

    // zero the 256 stamp cells (captured node, re-runs every replay)
    hipMemsetAsync((char*)d_ws + (size_t)WS_CTR*sizeof(float), 0, 1024, stream);

    lstm_persist<<<dim3(256), dim3(512), 0, stream>>>(
        x, done, h0, c0, w_ih, w_hh, b_ih, b_hh, Wp, bp, Wb, bb, out, ws);
}